// Round 1
// baseline (2754.501 us; speedup 1.0000x reference)
//
#include <hip/hip_runtime.h>
#include <hip/hip_bf16.h>
#include <cstdint>

#define N_NODES 4096
#define F_IN    1433
#define N_EDGE  131072

// ---------------- adjacency build ----------------

__global__ void scatter_edges_k(const int* __restrict__ e0, const int* __restrict__ e1,
                                float* __restrict__ A, int n, int ne) {
  int t = blockIdx.x * 256 + threadIdx.x;
  if (t >= ne) return;
  int u = e0[t], v = e1[t];
  if (u != v) {
    A[(size_t)u * n + v] = 1.0f;
    A[(size_t)v * n + u] = 1.0f;
  }
}

// deg = rowsum(A) + 2 (improved GCN), dinv = 1/sqrt(deg)
__global__ void deg_dinv_k(const float* __restrict__ A, float* __restrict__ dinv, int n) {
  int wid  = (blockIdx.x * blockDim.x + threadIdx.x) >> 6;
  int lane = threadIdx.x & 63;
  if (wid >= n) return;
  const float* row = A + (size_t)wid * n;
  float s = 0.f;
  for (int j = lane * 4; j < n; j += 256) {
    float4 v = *(const float4*)(row + j);
    s += (v.x + v.y) + (v.z + v.w);
  }
#pragma unroll
  for (int off = 32; off > 0; off >>= 1) s += __shfl_down(s, off, 64);
  if (lane == 0) {
    float d = s + 2.0f;
    dinv[wid] = d > 0.f ? 1.0f / sqrtf(d) : 0.f;
  }
}

// ---------------- f32 GEMM (C = A @ B), n multiple of 128 ----------------

__global__ __launch_bounds__(256) void gemm_f32_k(const float* __restrict__ A,
                                                  const float* __restrict__ B,
                                                  float* __restrict__ C, int n) {
  __shared__ float As[8][128];
  __shared__ float Bs[8][132];  // +4 pad
  int nb  = n >> 7;
  int bx  = blockIdx.x % nb;
  int by  = blockIdx.x / nb;
  int tid = threadIdx.x;
  int tr = tid >> 4, tc = tid & 15;
  int row0 = by << 7, col0 = bx << 7;
  float acc[8][8];
#pragma unroll
  for (int i = 0; i < 8; ++i)
#pragma unroll
    for (int j = 0; j < 8; ++j) acc[i][j] = 0.f;

  const int lar = tid >> 1, lak = (tid & 1) << 2;   // A loader: row, k-quad
  const int lbk = tid >> 5, lbc = (tid & 31) << 2;  // B loader: k, col-quad
  for (int k0 = 0; k0 < n; k0 += 8) {
    float4 av = *(const float4*)(A + (size_t)(row0 + lar) * n + k0 + lak);
    float4 bv = *(const float4*)(B + (size_t)(k0 + lbk) * n + col0 + lbc);
    __syncthreads();
    As[lak + 0][lar] = av.x;
    As[lak + 1][lar] = av.y;
    As[lak + 2][lar] = av.z;
    As[lak + 3][lar] = av.w;
    *(float4*)&Bs[lbk][lbc] = bv;
    __syncthreads();
#pragma unroll
    for (int k = 0; k < 8; ++k) {
      float4 a0 = *(const float4*)&As[k][tr * 8];
      float4 a1 = *(const float4*)&As[k][tr * 8 + 4];
      float4 b0 = *(const float4*)&Bs[k][tc * 8];
      float4 b1 = *(const float4*)&Bs[k][tc * 8 + 4];
      float a[8] = {a0.x, a0.y, a0.z, a0.w, a1.x, a1.y, a1.z, a1.w};
      float b[8] = {b0.x, b0.y, b0.z, b0.w, b1.x, b1.y, b1.z, b1.w};
#pragma unroll
      for (int i = 0; i < 8; ++i)
#pragma unroll
        for (int j = 0; j < 8; ++j) acc[i][j] += a[i] * b[j];
    }
  }
#pragma unroll
  for (int i = 0; i < 8; ++i) {
    float4 v0 = {acc[i][0], acc[i][1], acc[i][2], acc[i][3]};
    float4 v1 = {acc[i][4], acc[i][5], acc[i][6], acc[i][7]};
    float* cp = C + (size_t)(row0 + tr * 8 + i) * n + col0 + tc * 8;
    *(float4*)cp = v0;
    *(float4*)(cp + 4) = v1;
  }
}

// C = C + 2A, zero diagonal  (augment = (A+I)^2 * (1-I) = (A^2 + 2A) off-diag)
__global__ void aug_post_k(float* __restrict__ Cm, const float* __restrict__ A,
                           int n, int nbits) {
  size_t f4 = (size_t)blockIdx.x * 256 + threadIdx.x;
  size_t base = f4 * 4;
  if (base >= (size_t)n * n) return;
  float4 c = *(float4*)(Cm + base);
  float4 a = *(const float4*)(A + base);
  c.x += 2.f * a.x; c.y += 2.f * a.y; c.z += 2.f * a.z; c.w += 2.f * a.w;
  int row = (int)(base >> nbits);
  int col = (int)(base & (size_t)(n - 1));
  int d = row - col;
  if (d == 0) c.x = 0.f;
  else if (d == 1) c.y = 0.f;
  else if (d == 2) c.z = 0.f;
  else if (d == 3) c.w = 0.f;
  *(float4*)(Cm + base) = c;
}

// ---------------- Z = dinv_i * (X @ W), optional relu on X ----------------
// block dim3(32,8): tx = out col, ty = row in block
template <int K2>
__global__ void xw_scale_k(const float* __restrict__ X, const float* __restrict__ W,
                           const float* __restrict__ dinv, float* __restrict__ Z,
                           int n, int K1, int relu_in) {
  __shared__ float Xs[8][128];
  int tx = threadIdx.x, ty = threadIdx.y;
  int i0 = blockIdx.x * 8;
  int tid = ty * 32 + tx;
  float acc = 0.f;
  for (int k0 = 0; k0 < K1; k0 += 128) {
    __syncthreads();
#pragma unroll
    for (int l = 0; l < 4; ++l) {
      int idx = tid + l * 256;
      int r = idx >> 7, kk = idx & 127;
      float xv = (k0 + kk < K1) ? X[(size_t)(i0 + r) * K1 + k0 + kk] : 0.f;
      if (relu_in) xv = fmaxf(xv, 0.f);
      Xs[r][kk] = xv;
    }
    __syncthreads();
    if (tx < K2) {
      int lim = min(128, K1 - k0);
      for (int kk = 0; kk < lim; ++kk)
        acc += Xs[ty][kk] * W[(size_t)(k0 + kk) * K2 + tx];
    }
  }
  if (tx < K2) Z[(size_t)(i0 + ty) * K2 + tx] = dinv[i0 + ty] * acc;
}

// ---------------- out = act(dinv_i*(A@Z + 2*Z_i) + b) ----------------
// 32 rows/block; thread (rt = tid>>3, cg = tid&7) owns 1 row x 4 cols
template <int HC>
__global__ __launch_bounds__(256) void gcn_agg_k(const float* __restrict__ A,
                                                 const float* __restrict__ Z,
                                                 const float* __restrict__ dinv,
                                                 const float* __restrict__ bias,
                                                 float* __restrict__ out, int n, int relu) {
  __shared__ float As[32][68];
  __shared__ float Zs[64][32];
  int tid = threadIdx.x;
  int rt = tid >> 3, cg = tid & 7;
  int row0 = blockIdx.x * 32;
  float acc[4] = {0.f, 0.f, 0.f, 0.f};
  for (int j0 = 0; j0 < n; j0 += 64) {
    __syncthreads();
#pragma unroll
    for (int l = 0; l < 2; ++l) {
      int f = tid + l * 256;
      int r = f >> 4, q = f & 15;
      *(float4*)&As[r][q * 4] = *(const float4*)(A + (size_t)(row0 + r) * n + j0 + q * 4);
    }
    if (HC == 32) {
#pragma unroll
      for (int l = 0; l < 2; ++l) {
        int f = tid + l * 256;
        int r = f >> 3, q = f & 7;
        *(float4*)&Zs[r][q * 4] = *(const float4*)(Z + (size_t)(j0 + r) * 32 + q * 4);
      }
    } else {
      for (int l = tid; l < 64 * HC; l += 256) {
        int r = l / HC, q = l - r * HC;
        Zs[r][q] = Z[(size_t)(j0 + r) * HC + q];
      }
    }
    __syncthreads();
#pragma unroll
    for (int j = 0; j < 64; ++j) {
      float av = As[rt][j];
      float4 zv = *(const float4*)&Zs[j][cg * 4];
      acc[0] += av * zv.x;
      acc[1] += av * zv.y;
      acc[2] += av * zv.z;
      acc[3] += av * zv.w;
    }
  }
  int row = row0 + rt;
  float di = dinv[row];
#pragma unroll
  for (int q = 0; q < 4; ++q) {
    int c = cg * 4 + q;
    if (c < HC) {
      float zi = Z[(size_t)row * HC + c];
      float v = di * (acc[q] + 2.f * zi) + bias[c];
      if (relu) v = fmaxf(v, 0.f);
      out[(size_t)row * HC + c] = v;
    }
  }
}

// ---------------- top-k machinery ----------------

__global__ void score_k(const float* __restrict__ h, const float* __restrict__ p,
                        float* __restrict__ score, int n) {
  int i = blockIdx.x * 256 + threadIdx.x;
  if (i >= n) return;
  float s = 0.f, pn = 0.f;
#pragma unroll
  for (int c = 0; c < 32; ++c) {
    float pc = p[c];
    s += h[(size_t)i * 32 + c] * pc;
    pn += pc * pc;
  }
  score[i] = tanhf(s / sqrtf(pn));
}

// exact rank selection: rank by (score desc, index asc) == jax.lax.top_k order
__global__ void topk_k(const float* __restrict__ score, int* __restrict__ perm,
                       float* __restrict__ vals, int n, int k) {
  __shared__ float sc[256];
  int i = blockIdx.x * 256 + threadIdx.x;
  float si = score[i];
  int rank = 0;
  for (int j0 = 0; j0 < n; j0 += 256) {
    __syncthreads();
    sc[threadIdx.x] = score[j0 + threadIdx.x];
    __syncthreads();
#pragma unroll 8
    for (int jj = 0; jj < 256; ++jj) {
      float sj = sc[jj];
      rank += (sj > si) || ((sj == si) && ((j0 + jj) < i));
    }
  }
  if (rank < k) { perm[rank] = i; vals[rank] = si; }
}

__global__ void pool_h_k(const float* __restrict__ h, const int* __restrict__ perm,
                         const float* __restrict__ vals, float* __restrict__ out, int k) {
  int idx = blockIdx.x * 256 + threadIdx.x;
  if (idx >= k * 32) return;
  int r = idx >> 5, c = idx & 31;
  out[idx] = h[(size_t)perm[r] * 32 + c] * vals[r];
}

__global__ void pool_A_k(const float* __restrict__ Aaug, const int* __restrict__ perm,
                         float* __restrict__ out, int n, int kbits) {
  size_t idx = (size_t)blockIdx.x * 256 + threadIdx.x;
  int k = 1 << kbits;
  if (idx >= (size_t)k * k) return;
  int r = (int)(idx >> kbits);
  int s = (int)(idx & (size_t)(k - 1));
  out[idx] = Aaug[(size_t)perm[r] * n + perm[s]];
}

__global__ void scatter_add_k(float* __restrict__ buf, const int* __restrict__ perm,
                              const float* __restrict__ h, int k) {
  int idx = blockIdx.x * 256 + threadIdx.x;
  if (idx >= k * 32) return;
  int r = idx >> 5, c = idx & 31;
  buf[(size_t)perm[r] * 32 + c] += h[idx];
}

__global__ void logsoftmax_k(const float* __restrict__ z, float* __restrict__ out, int n) {
  int i = blockIdx.x * 256 + threadIdx.x;
  if (i >= n) return;
  const float* zp = z + (size_t)i * 7;
  float m = zp[0];
#pragma unroll
  for (int c = 1; c < 7; ++c) m = fmaxf(m, zp[c]);
  float ssum = 0.f;
#pragma unroll
  for (int c = 0; c < 7; ++c) ssum += expf(zp[c] - m);
  float ls = logf(ssum);
  float* op = out + (size_t)i * 7;
#pragma unroll
  for (int c = 0; c < 7; ++c) op[c] = zp[c] - m - ls;
}

// ---------------- host orchestration ----------------

extern "C" void kernel_launch(void* const* d_in, const int* in_sizes, int n_in,
                              void* d_out, int out_size, void* d_ws, size_t ws_size,
                              hipStream_t stream) {
  (void)in_sizes; (void)n_in; (void)out_size; (void)ws_size;
  const float* x   = (const float*)d_in[0];
  const int*  eidx = (const int*)d_in[1];
  const float* Wi  = (const float*)d_in[2];
  const float* bi  = (const float*)d_in[3];
  const float* dW  = (const float*)d_in[4];
  const float* db  = (const float*)d_in[5];
  const float* pp  = (const float*)d_in[6];
  const float* uW  = (const float*)d_in[7];
  const float* ub  = (const float*)d_in[8];
  const float* Wf  = (const float*)d_in[9];
  const float* bf  = (const float*)d_in[10];
  float* outp = (float*)d_out;

  char* ws = (char*)d_ws;
  size_t off = 0;
  auto alloc = [&](size_t bytes) -> char* {
    char* p = ws + off;
    off += (bytes + 255) & ~(size_t)255;
    return p;
  };
  const int n0 = 4096, n1 = 2048, n2 = 1024, n3 = 512;
  float* A     = (float*)alloc((size_t)n0 * n0 * 4);
  float* Cb    = (float*)alloc((size_t)n0 * n0 * 4);
  float* As1   = (float*)alloc((size_t)n1 * n1 * 4);
  float* As2   = (float*)alloc((size_t)n2 * n2 * 4);
  float* A3    = (float*)alloc((size_t)n3 * n3 * 4);
  float* dinv0 = (float*)alloc(n0 * 4);
  float* dinv1 = (float*)alloc(n1 * 4);
  float* dinv2 = (float*)alloc(n2 * 4);
  float* dinv3 = (float*)alloc(n3 * 4);
  float* Zb    = (float*)alloc((size_t)n0 * 32 * 4);
  float* x0    = (float*)alloc((size_t)n0 * 32 * 4);
  float* xs0   = (float*)alloc((size_t)n0 * 32 * 4);
  float* xs1   = (float*)alloc((size_t)n1 * 32 * 4);
  float* xs2   = (float*)alloc((size_t)n2 * 32 * 4);
  float* hA    = (float*)alloc((size_t)n0 * 32 * 4);
  float* hB    = (float*)alloc((size_t)n0 * 32 * 4);
  float* scb   = (float*)alloc(n0 * 4);
  float* valsb = (float*)alloc(n0 * 4);
  int* perm1   = (int*)alloc(n1 * 4);
  int* perm2   = (int*)alloc(n2 * 4);
  int* perm3   = (int*)alloc(n3 * 4);
  float* otmp  = (float*)alloc((size_t)n0 * 7 * 4);

  // adjacency
  hipMemsetAsync(A, 0, (size_t)n0 * n0 * 4, stream);
  scatter_edges_k<<<N_EDGE / 256, 256, 0, stream>>>(eidx, eidx + N_EDGE, A, n0, N_EDGE);
  deg_dinv_k<<<n0 / 4, 256, 0, stream>>>(A, dinv0, n0);

  // gcn0: x0 = relu(gcn(x, A, Wi, bi))
  xw_scale_k<32><<<n0 / 8, dim3(32, 8), 0, stream>>>(x, Wi, dinv0, Zb, n0, F_IN, 0);
  gcn_agg_k<32><<<n0 / 32, 256, 0, stream>>>(A, Zb, dinv0, bi, x0, n0, 1);
  // gcn1: xs0 = relu(gcn(x0, A, dW0, db0))
  xw_scale_k<32><<<n0 / 8, dim3(32, 8), 0, stream>>>(x0, dW, dinv0, Zb, n0, 32, 0);
  gcn_agg_k<32><<<n0 / 32, 256, 0, stream>>>(A, Zb, dinv0, db, xs0, n0, 1);

  // ---- level 1 ----
  gemm_f32_k<<<(n0 / 128) * (n0 / 128), 256, 0, stream>>>(A, A, Cb, n0);
  aug_post_k<<<(int)(((size_t)n0 * n0 / 4 + 255) / 256), 256, 0, stream>>>(Cb, A, n0, 12);
  score_k<<<n0 / 256, 256, 0, stream>>>(xs0, pp, scb, n0);
  topk_k<<<n0 / 256, 256, 0, stream>>>(scb, perm1, valsb, n0, n1);
  pool_h_k<<<n1 * 32 / 256, 256, 0, stream>>>(xs0, perm1, valsb, hA, n1);
  pool_A_k<<<(int)(((size_t)n1 * n1 + 255) / 256), 256, 0, stream>>>(Cb, perm1, As1, n0, 11);
  deg_dinv_k<<<n1 / 4, 256, 0, stream>>>(As1, dinv1, n1);
  xw_scale_k<32><<<n1 / 8, dim3(32, 8), 0, stream>>>(hA, dW + 1024, dinv1, Zb, n1, 32, 0);
  gcn_agg_k<32><<<n1 / 32, 256, 0, stream>>>(As1, Zb, dinv1, db + 32, xs1, n1, 1);

  // ---- level 2 ----
  gemm_f32_k<<<(n1 / 128) * (n1 / 128), 256, 0, stream>>>(As1, As1, Cb, n1);
  aug_post_k<<<(int)(((size_t)n1 * n1 / 4 + 255) / 256), 256, 0, stream>>>(Cb, As1, n1, 11);
  score_k<<<n1 / 256, 256, 0, stream>>>(xs1, pp + 32, scb, n1);
  topk_k<<<n1 / 256, 256, 0, stream>>>(scb, perm2, valsb, n1, n2);
  pool_h_k<<<n2 * 32 / 256, 256, 0, stream>>>(xs1, perm2, valsb, hA, n2);
  pool_A_k<<<(int)(((size_t)n2 * n2 + 255) / 256), 256, 0, stream>>>(Cb, perm2, As2, n1, 10);
  deg_dinv_k<<<n2 / 4, 256, 0, stream>>>(As2, dinv2, n2);
  xw_scale_k<32><<<n2 / 8, dim3(32, 8), 0, stream>>>(hA, dW + 2048, dinv2, Zb, n2, 32, 0);
  gcn_agg_k<32><<<n2 / 32, 256, 0, stream>>>(As2, Zb, dinv2, db + 64, xs2, n2, 1);

  // ---- level 3 ----
  gemm_f32_k<<<(n2 / 128) * (n2 / 128), 256, 0, stream>>>(As2, As2, Cb, n2);
  aug_post_k<<<(int)(((size_t)n2 * n2 / 4 + 255) / 256), 256, 0, stream>>>(Cb, As2, n2, 10);
  score_k<<<n2 / 256, 256, 0, stream>>>(xs2, pp + 64, scb, n2);
  topk_k<<<n2 / 256, 256, 0, stream>>>(scb, perm3, valsb, n2, n3);
  pool_h_k<<<n3 * 32 / 256, 256, 0, stream>>>(xs2, perm3, valsb, hA, n3);
  pool_A_k<<<(int)(((size_t)n3 * n3 + 255) / 256), 256, 0, stream>>>(Cb, perm3, A3, n2, 9);
  deg_dinv_k<<<n3 / 4, 256, 0, stream>>>(A3, dinv3, n3);
  xw_scale_k<32><<<n3 / 8, dim3(32, 8), 0, stream>>>(hA, dW + 3072, dinv3, Zb, n3, 32, 0);
  gcn_agg_k<32><<<n3 / 32, 256, 0, stream>>>(A3, Zb, dinv3, db + 96, hB, n3, 1);

  // ---- up path ----
  hipMemcpyAsync(hA, xs2, (size_t)n2 * 32 * 4, hipMemcpyDeviceToDevice, stream);
  scatter_add_k<<<n3 * 32 / 256, 256, 0, stream>>>(hA, perm3, hB, n3);
  xw_scale_k<32><<<n2 / 8, dim3(32, 8), 0, stream>>>(hA, uW, dinv2, Zb, n2, 32, 0);
  gcn_agg_k<32><<<n2 / 32, 256, 0, stream>>>(As2, Zb, dinv2, ub, hB, n2, 1);

  hipMemcpyAsync(hA, xs1, (size_t)n1 * 32 * 4, hipMemcpyDeviceToDevice, stream);
  scatter_add_k<<<n2 * 32 / 256, 256, 0, stream>>>(hA, perm2, hB, n2);
  xw_scale_k<32><<<n1 / 8, dim3(32, 8), 0, stream>>>(hA, uW + 1024, dinv1, Zb, n1, 32, 0);
  gcn_agg_k<32><<<n1 / 32, 256, 0, stream>>>(As1, Zb, dinv1, ub + 32, hB, n1, 1);

  hipMemcpyAsync(hA, xs0, (size_t)n0 * 32 * 4, hipMemcpyDeviceToDevice, stream);
  scatter_add_k<<<n1 * 32 / 256, 256, 0, stream>>>(hA, perm1, hB, n1);
  xw_scale_k<32><<<n0 / 8, dim3(32, 8), 0, stream>>>(hA, uW + 2048, dinv0, Zb, n0, 32, 0);
  gcn_agg_k<32><<<n0 / 32, 256, 0, stream>>>(A, Zb, dinv0, ub + 64, hB, n0, 0);

  // final: x = relu(h); out = gcn(x, A, Wf, bf); log_softmax
  xw_scale_k<7><<<n0 / 8, dim3(32, 8), 0, stream>>>(hB, Wf, dinv0, Zb, n0, 32, 1);
  gcn_agg_k<7><<<n0 / 32, 256, 0, stream>>>(A, Zb, dinv0, bf, otmp, n0, 0);
  logsoftmax_k<<<n0 / 256, 256, 0, stream>>>(otmp, outp, n0);
}

// Round 2
// 1308.798 us; speedup vs baseline: 2.1046x; 2.1046x over previous
//
#include <hip/hip_runtime.h>
#include <hip/hip_bf16.h>
#include <cstdint>

#define N_NODES 4096
#define F_IN    1433
#define N_EDGE  131072

typedef short short8v __attribute__((ext_vector_type(8)));
typedef float f32x4 __attribute__((ext_vector_type(4)));

#define GLOBAL_AS __attribute__((address_space(1)))
#define LDS_AS    __attribute__((address_space(3)))

__device__ __forceinline__ void gload_lds16(const void* g, void* l) {
  __builtin_amdgcn_global_load_lds((const GLOBAL_AS void*)g, (LDS_AS void*)l, 16, 0, 0);
}

// ---------------- adjacency build ----------------

__global__ void scatter_edges_k(const int* __restrict__ e0, const int* __restrict__ e1,
                                float* __restrict__ A, unsigned short* __restrict__ Ab,
                                int n, int ne) {
  int t = blockIdx.x * 256 + threadIdx.x;
  if (t >= ne) return;
  int u = e0[t], v = e1[t];
  if (u != v) {
    A[(size_t)u * n + v] = 1.0f;
    A[(size_t)v * n + u] = 1.0f;
    Ab[(size_t)u * n + v] = 0x3F80;  // bf16 1.0
    Ab[(size_t)v * n + u] = 0x3F80;
  }
}

// deg = rowsum(A) + 2 (improved GCN), dinv = 1/sqrt(deg)
__global__ void deg_dinv_k(const float* __restrict__ A, float* __restrict__ dinv, int n) {
  int wid  = (blockIdx.x * blockDim.x + threadIdx.x) >> 6;
  int lane = threadIdx.x & 63;
  if (wid >= n) return;
  const float* row = A + (size_t)wid * n;
  float s = 0.f;
  for (int j = lane * 4; j < n; j += 256) {
    float4 v = *(const float4*)(row + j);
    s += (v.x + v.y) + (v.z + v.w);
  }
#pragma unroll
  for (int off = 32; off > 0; off >>= 1) s += __shfl_down(s, off, 64);
  if (lane == 0) {
    float d = s + 2.0f;
    dinv[wid] = d > 0.f ? 1.0f / sqrtf(d) : 0.f;
  }
}

// ---------------- bf16 MFMA GEMM for augment: C = M@M + 2M, zero diag ----------
// M symmetric bf16 (values exact small integers); C f32. n multiple of 128.
// m97 structure: 128x128 tile, BK=32, 4 waves, global_load_lds x16, dbuf LDS.

__global__ __launch_bounds__(256) void gemm_bf16_aug_k(const __hip_bfloat16* __restrict__ Mb,
                                                       float* __restrict__ C, int n) {
  __shared__ short lds[2][2][128 * 32];
  int nb  = n >> 7;
  int bx  = blockIdx.x % nb;
  int by  = blockIdx.x / nb;
  int row0 = by << 7, col0 = bx << 7;
  int tid = threadIdx.x;
  int wv = tid >> 6, ln = tid & 63;
  int lr = ln & 15, kh = ln >> 4;
  int wr = wv >> 1, wc = wv & 1;

  f32x4 acc[4][4] = {};

  auto stage = [&](int buf, int k0) {
#pragma unroll
    for (int t = 0; t < 2; ++t) {
      int rbase = t ? col0 : row0;  // A tile rows = row0.., B^T tile rows = col0..
      short* base = &lds[buf][t][0];
#pragma unroll
      for (int l = 0; l < 2; ++l) {
        int uoff = l * 4096 + wv * 1024;          // wave-uniform LDS byte offset
        int poff = uoff + ln * 16;                // per-lane byte offset
        int row  = poff >> 6;                     // 64B per row (32 bf16)
        int colb = poff & 63;
        const char* g = (const char*)(Mb + (size_t)(rbase + row) * n + k0) + colb;
        gload_lds16(g, (char*)base + uoff);
      }
    }
  };

  int nt = n >> 5;
  stage(0, 0);
  int cur = 0;
  for (int kt = 0; kt < nt; ++kt) {
    __syncthreads();  // drains vmcnt(0): staged buf[cur] is ready
    if (kt + 1 < nt) stage(cur ^ 1, (kt + 1) << 5);
    const short* Ab = &lds[cur][0][0];
    const short* Bb = &lds[cur][1][0];
    short8v af[4], bfr[4];
#pragma unroll
    for (int m = 0; m < 4; ++m)
      af[m] = *(const short8v*)(Ab + (wr * 64 + m * 16 + lr) * 32 + kh * 8);
#pragma unroll
    for (int q = 0; q < 4; ++q)
      bfr[q] = *(const short8v*)(Bb + (wc * 64 + q * 16 + lr) * 32 + kh * 8);
#pragma unroll
    for (int m = 0; m < 4; ++m)
#pragma unroll
      for (int q = 0; q < 4; ++q)
        acc[m][q] = __builtin_amdgcn_mfma_f32_16x16x32_bf16(af[m], bfr[q], acc[m][q], 0, 0, 0);
    cur ^= 1;
  }

  // epilogue: C = acc + 2*M, diag = 0
#pragma unroll
  for (int m = 0; m < 4; ++m) {
    int rb = row0 + wr * 64 + m * 16 + kh * 4;
#pragma unroll
    for (int q = 0; q < 4; ++q) {
      int col = col0 + wc * 64 + q * 16 + lr;
#pragma unroll
      for (int r = 0; r < 4; ++r) {
        int row = rb + r;
        float v = acc[m][q][r] + 2.0f * __bfloat162float(Mb[(size_t)row * n + col]);
        if (row == col) v = 0.f;
        C[(size_t)row * n + col] = v;
      }
    }
  }
}

// ---------------- f32 GEMM (C = A @ B), n multiple of 128 (level-3 only) -------

__global__ __launch_bounds__(256) void gemm_f32_k(const float* __restrict__ A,
                                                  const float* __restrict__ B,
                                                  float* __restrict__ C, int n) {
  __shared__ float As[8][128];
  __shared__ float Bs[8][132];  // +4 pad
  int nb  = n >> 7;
  int bx  = blockIdx.x % nb;
  int by  = blockIdx.x / nb;
  int tid = threadIdx.x;
  int tr = tid >> 4, tc = tid & 15;
  int row0 = by << 7, col0 = bx << 7;
  float acc[8][8];
#pragma unroll
  for (int i = 0; i < 8; ++i)
#pragma unroll
    for (int j = 0; j < 8; ++j) acc[i][j] = 0.f;

  const int lar = tid >> 1, lak = (tid & 1) << 2;
  const int lbk = tid >> 5, lbc = (tid & 31) << 2;
  for (int k0 = 0; k0 < n; k0 += 8) {
    float4 av = *(const float4*)(A + (size_t)(row0 + lar) * n + k0 + lak);
    float4 bv = *(const float4*)(B + (size_t)(k0 + lbk) * n + col0 + lbc);
    __syncthreads();
    As[lak + 0][lar] = av.x;
    As[lak + 1][lar] = av.y;
    As[lak + 2][lar] = av.z;
    As[lak + 3][lar] = av.w;
    *(float4*)&Bs[lbk][lbc] = bv;
    __syncthreads();
#pragma unroll
    for (int k = 0; k < 8; ++k) {
      float4 a0 = *(const float4*)&As[k][tr * 8];
      float4 a1 = *(const float4*)&As[k][tr * 8 + 4];
      float4 b0 = *(const float4*)&Bs[k][tc * 8];
      float4 b1 = *(const float4*)&Bs[k][tc * 8 + 4];
      float a[8] = {a0.x, a0.y, a0.z, a0.w, a1.x, a1.y, a1.z, a1.w};
      float b[8] = {b0.x, b0.y, b0.z, b0.w, b1.x, b1.y, b1.z, b1.w};
#pragma unroll
      for (int i = 0; i < 8; ++i)
#pragma unroll
        for (int j = 0; j < 8; ++j) acc[i][j] += a[i] * b[j];
    }
  }
#pragma unroll
  for (int i = 0; i < 8; ++i) {
    float4 v0 = {acc[i][0], acc[i][1], acc[i][2], acc[i][3]};
    float4 v1 = {acc[i][4], acc[i][5], acc[i][6], acc[i][7]};
    float* cp = C + (size_t)(row0 + tr * 8 + i) * n + col0 + tc * 8;
    *(float4*)cp = v0;
    *(float4*)(cp + 4) = v1;
  }
}

// C = C + 2A, zero diagonal (level-3 only)
__global__ void aug_post_k(float* __restrict__ Cm, const float* __restrict__ A,
                           int n, int nbits) {
  size_t f4 = (size_t)blockIdx.x * 256 + threadIdx.x;
  size_t base = f4 * 4;
  if (base >= (size_t)n * n) return;
  float4 c = *(float4*)(Cm + base);
  float4 a = *(const float4*)(A + base);
  c.x += 2.f * a.x; c.y += 2.f * a.y; c.z += 2.f * a.z; c.w += 2.f * a.w;
  int row = (int)(base >> nbits);
  int col = (int)(base & (size_t)(n - 1));
  int d = row - col;
  if (d == 0) c.x = 0.f;
  else if (d == 1) c.y = 0.f;
  else if (d == 2) c.z = 0.f;
  else if (d == 3) c.w = 0.f;
  *(float4*)(Cm + base) = c;
}

// ---------------- Z = dinv_i * (X @ W), optional relu on X ----------------
template <int K2>
__global__ void xw_scale_k(const float* __restrict__ X, const float* __restrict__ W,
                           const float* __restrict__ dinv, float* __restrict__ Z,
                           int n, int K1, int relu_in) {
  __shared__ float Xs[8][128];
  int tx = threadIdx.x, ty = threadIdx.y;
  int i0 = blockIdx.x * 8;
  int tid = ty * 32 + tx;
  float acc = 0.f;
  for (int k0 = 0; k0 < K1; k0 += 128) {
    __syncthreads();
#pragma unroll
    for (int l = 0; l < 4; ++l) {
      int idx = tid + l * 256;
      int r = idx >> 7, kk = idx & 127;
      float xv = (k0 + kk < K1) ? X[(size_t)(i0 + r) * K1 + k0 + kk] : 0.f;
      if (relu_in) xv = fmaxf(xv, 0.f);
      Xs[r][kk] = xv;
    }
    __syncthreads();
    if (tx < K2) {
      int lim = min(128, K1 - k0);
      for (int kk = 0; kk < lim; ++kk)
        acc += Xs[ty][kk] * W[(size_t)(k0 + kk) * K2 + tx];
    }
  }
  if (tx < K2) Z[(size_t)(i0 + ty) * K2 + tx] = dinv[i0 + ty] * acc;
}

// ---------------- out = act(dinv_i*(A@Z + 2*Z_i) + b) ----------------
template <int HC>
__global__ __launch_bounds__(256) void gcn_agg_k(const float* __restrict__ A,
                                                 const float* __restrict__ Z,
                                                 const float* __restrict__ dinv,
                                                 const float* __restrict__ bias,
                                                 float* __restrict__ out, int n, int relu) {
  __shared__ float As[32][68];
  __shared__ float Zs[64][32];
  int tid = threadIdx.x;
  int rt = tid >> 3, cg = tid & 7;
  int row0 = blockIdx.x * 32;
  float acc[4] = {0.f, 0.f, 0.f, 0.f};
  for (int j0 = 0; j0 < n; j0 += 64) {
    __syncthreads();
#pragma unroll
    for (int l = 0; l < 2; ++l) {
      int f = tid + l * 256;
      int r = f >> 4, q = f & 15;
      *(float4*)&As[r][q * 4] = *(const float4*)(A + (size_t)(row0 + r) * n + j0 + q * 4);
    }
    if (HC == 32) {
#pragma unroll
      for (int l = 0; l < 2; ++l) {
        int f = tid + l * 256;
        int r = f >> 3, q = f & 7;
        *(float4*)&Zs[r][q * 4] = *(const float4*)(Z + (size_t)(j0 + r) * 32 + q * 4);
      }
    } else {
      for (int l = tid; l < 64 * HC; l += 256) {
        int r = l / HC, q = l - r * HC;
        Zs[r][q] = Z[(size_t)(j0 + r) * HC + q];
      }
    }
    __syncthreads();
#pragma unroll
    for (int j = 0; j < 64; ++j) {
      float av = As[rt][j];
      float4 zv = *(const float4*)&Zs[j][cg * 4];
      acc[0] += av * zv.x;
      acc[1] += av * zv.y;
      acc[2] += av * zv.z;
      acc[3] += av * zv.w;
    }
  }
  int row = row0 + rt;
  float di = dinv[row];
#pragma unroll
  for (int q = 0; q < 4; ++q) {
    int c = cg * 4 + q;
    if (c < HC) {
      float zi = Z[(size_t)row * HC + c];
      float v = di * (acc[q] + 2.f * zi) + bias[c];
      if (relu) v = fmaxf(v, 0.f);
      out[(size_t)row * HC + c] = v;
    }
  }
}

// ---------------- top-k machinery ----------------

__global__ void score_k(const float* __restrict__ h, const float* __restrict__ p,
                        float* __restrict__ score, int n) {
  int i = blockIdx.x * 256 + threadIdx.x;
  if (i >= n) return;
  float s = 0.f, pn = 0.f;
#pragma unroll
  for (int c = 0; c < 32; ++c) {
    float pc = p[c];
    s += h[(size_t)i * 32 + c] * pc;
    pn += pc * pc;
  }
  score[i] = tanhf(s / sqrtf(pn));
}

__global__ void topk_k(const float* __restrict__ score, int* __restrict__ perm,
                       float* __restrict__ vals, int n, int k) {
  __shared__ float sc[256];
  int i = blockIdx.x * 256 + threadIdx.x;
  float si = score[i];
  int rank = 0;
  for (int j0 = 0; j0 < n; j0 += 256) {
    __syncthreads();
    sc[threadIdx.x] = score[j0 + threadIdx.x];
    __syncthreads();
#pragma unroll 8
    for (int jj = 0; jj < 256; ++jj) {
      float sj = sc[jj];
      rank += (sj > si) || ((sj == si) && ((j0 + jj) < i));
    }
  }
  if (rank < k) { perm[rank] = i; vals[rank] = si; }
}

__global__ void pool_h_k(const float* __restrict__ h, const int* __restrict__ perm,
                         const float* __restrict__ vals, float* __restrict__ out, int k) {
  int idx = blockIdx.x * 256 + threadIdx.x;
  if (idx >= k * 32) return;
  int r = idx >> 5, c = idx & 31;
  out[idx] = h[(size_t)perm[r] * 32 + c] * vals[r];
}

// gather pooled adjacency; optionally also write bf16 copy (exact small ints)
__global__ void pool_A_k(const float* __restrict__ Aaug, const int* __restrict__ perm,
                         float* __restrict__ out, unsigned short* __restrict__ outb,
                         int n, int kbits) {
  size_t idx = (size_t)blockIdx.x * 256 + threadIdx.x;
  int k = 1 << kbits;
  if (idx >= (size_t)k * k) return;
  int r = (int)(idx >> kbits);
  int s = (int)(idx & (size_t)(k - 1));
  float v = Aaug[(size_t)perm[r] * n + perm[s]];
  out[idx] = v;
  if (outb) {
    union { float f; unsigned u; } cvt; cvt.f = v;
    outb[idx] = (unsigned short)(cvt.u >> 16);  // exact: v is small integer
  }
}

__global__ void scatter_add_k(float* __restrict__ buf, const int* __restrict__ perm,
                              const float* __restrict__ h, int k) {
  int idx = blockIdx.x * 256 + threadIdx.x;
  if (idx >= k * 32) return;
  int r = idx >> 5, c = idx & 31;
  buf[(size_t)perm[r] * 32 + c] += h[idx];
}

__global__ void logsoftmax_k(const float* __restrict__ z, float* __restrict__ out, int n) {
  int i = blockIdx.x * 256 + threadIdx.x;
  if (i >= n) return;
  const float* zp = z + (size_t)i * 7;
  float m = zp[0];
#pragma unroll
  for (int c = 1; c < 7; ++c) m = fmaxf(m, zp[c]);
  float ssum = 0.f;
#pragma unroll
  for (int c = 0; c < 7; ++c) ssum += expf(zp[c] - m);
  float ls = logf(ssum);
  float* op = out + (size_t)i * 7;
#pragma unroll
  for (int c = 0; c < 7; ++c) op[c] = zp[c] - m - ls;
}

// ---------------- host orchestration ----------------

extern "C" void kernel_launch(void* const* d_in, const int* in_sizes, int n_in,
                              void* d_out, int out_size, void* d_ws, size_t ws_size,
                              hipStream_t stream) {
  (void)in_sizes; (void)n_in; (void)out_size; (void)ws_size;
  const float* x   = (const float*)d_in[0];
  const int*  eidx = (const int*)d_in[1];
  const float* Wi  = (const float*)d_in[2];
  const float* bi  = (const float*)d_in[3];
  const float* dW  = (const float*)d_in[4];
  const float* db  = (const float*)d_in[5];
  const float* pp  = (const float*)d_in[6];
  const float* uW  = (const float*)d_in[7];
  const float* ub  = (const float*)d_in[8];
  const float* Wf  = (const float*)d_in[9];
  const float* bf  = (const float*)d_in[10];
  float* outp = (float*)d_out;

  char* ws = (char*)d_ws;
  size_t off = 0;
  auto alloc = [&](size_t bytes) -> char* {
    char* p = ws + off;
    off += (bytes + 255) & ~(size_t)255;
    return p;
  };
  const int n0 = 4096, n1 = 2048, n2 = 1024, n3 = 512;
  float* A     = (float*)alloc((size_t)n0 * n0 * 4);
  float* Cb    = (float*)alloc((size_t)n0 * n0 * 4);
  float* As1   = (float*)alloc((size_t)n1 * n1 * 4);
  float* As2   = (float*)alloc((size_t)n2 * n2 * 4);
  float* A3    = (float*)alloc((size_t)n3 * n3 * 4);
  unsigned short* Abf   = (unsigned short*)alloc((size_t)n0 * n0 * 2);
  unsigned short* As1bf = (unsigned short*)alloc((size_t)n1 * n1 * 2);
  float* dinv0 = (float*)alloc(n0 * 4);
  float* dinv1 = (float*)alloc(n1 * 4);
  float* dinv2 = (float*)alloc(n2 * 4);
  float* dinv3 = (float*)alloc(n3 * 4);
  float* Zb    = (float*)alloc((size_t)n0 * 32 * 4);
  float* x0    = (float*)alloc((size_t)n0 * 32 * 4);
  float* xs0   = (float*)alloc((size_t)n0 * 32 * 4);
  float* xs1   = (float*)alloc((size_t)n1 * 32 * 4);
  float* xs2   = (float*)alloc((size_t)n2 * 32 * 4);
  float* hA    = (float*)alloc((size_t)n0 * 32 * 4);
  float* hB    = (float*)alloc((size_t)n0 * 32 * 4);
  float* scb   = (float*)alloc(n0 * 4);
  float* valsb = (float*)alloc(n0 * 4);
  int* perm1   = (int*)alloc(n1 * 4);
  int* perm2   = (int*)alloc(n2 * 4);
  int* perm3   = (int*)alloc(n3 * 4);
  float* otmp  = (float*)alloc((size_t)n0 * 7 * 4);

  // adjacency (f32 + bf16 copies)
  hipMemsetAsync(A, 0, (size_t)n0 * n0 * 4, stream);
  hipMemsetAsync(Abf, 0, (size_t)n0 * n0 * 2, stream);
  scatter_edges_k<<<N_EDGE / 256, 256, 0, stream>>>(eidx, eidx + N_EDGE, A, Abf, n0, N_EDGE);
  deg_dinv_k<<<n0 / 4, 256, 0, stream>>>(A, dinv0, n0);

  // gcn0: x0 = relu(gcn(x, A, Wi, bi))
  xw_scale_k<32><<<n0 / 8, dim3(32, 8), 0, stream>>>(x, Wi, dinv0, Zb, n0, F_IN, 0);
  gcn_agg_k<32><<<n0 / 32, 256, 0, stream>>>(A, Zb, dinv0, bi, x0, n0, 1);
  // gcn1: xs0 = relu(gcn(x0, A, dW0, db0))
  xw_scale_k<32><<<n0 / 8, dim3(32, 8), 0, stream>>>(x0, dW, dinv0, Zb, n0, 32, 0);
  gcn_agg_k<32><<<n0 / 32, 256, 0, stream>>>(A, Zb, dinv0, db, xs0, n0, 1);

  // ---- level 1: Cb = A@A + 2A (diag 0) via bf16 MFMA ----
  gemm_bf16_aug_k<<<(n0 / 128) * (n0 / 128), 256, 0, stream>>>((const __hip_bfloat16*)Abf, Cb, n0);
  score_k<<<n0 / 256, 256, 0, stream>>>(xs0, pp, scb, n0);
  topk_k<<<n0 / 256, 256, 0, stream>>>(scb, perm1, valsb, n0, n1);
  pool_h_k<<<n1 * 32 / 256, 256, 0, stream>>>(xs0, perm1, valsb, hA, n1);
  pool_A_k<<<(int)(((size_t)n1 * n1 + 255) / 256), 256, 0, stream>>>(Cb, perm1, As1, As1bf, n0, 11);
  deg_dinv_k<<<n1 / 4, 256, 0, stream>>>(As1, dinv1, n1);
  xw_scale_k<32><<<n1 / 8, dim3(32, 8), 0, stream>>>(hA, dW + 1024, dinv1, Zb, n1, 32, 0);
  gcn_agg_k<32><<<n1 / 32, 256, 0, stream>>>(As1, Zb, dinv1, db + 32, xs1, n1, 1);

  // ---- level 2: Cb = As1@As1 + 2As1 via bf16 MFMA (values <= ~17, exact) ----
  gemm_bf16_aug_k<<<(n1 / 128) * (n1 / 128), 256, 0, stream>>>((const __hip_bfloat16*)As1bf, Cb, n1);
  score_k<<<n1 / 256, 256, 0, stream>>>(xs1, pp + 32, scb, n1);
  topk_k<<<n1 / 256, 256, 0, stream>>>(scb, perm2, valsb, n1, n2);
  pool_h_k<<<n2 * 32 / 256, 256, 0, stream>>>(xs1, perm2, valsb, hA, n2);
  pool_A_k<<<(int)(((size_t)n2 * n2 + 255) / 256), 256, 0, stream>>>(Cb, perm2, As2, nullptr, n1, 10);
  deg_dinv_k<<<n2 / 4, 256, 0, stream>>>(As2, dinv2, n2);
  xw_scale_k<32><<<n2 / 8, dim3(32, 8), 0, stream>>>(hA, dW + 2048, dinv2, Zb, n2, 32, 0);
  gcn_agg_k<32><<<n2 / 32, 256, 0, stream>>>(As2, Zb, dinv2, db + 64, xs2, n2, 1);

  // ---- level 3 (f32: As2 values not bf16-exact) ----
  gemm_f32_k<<<(n2 / 128) * (n2 / 128), 256, 0, stream>>>(As2, As2, Cb, n2);
  aug_post_k<<<(int)(((size_t)n2 * n2 / 4 + 255) / 256), 256, 0, stream>>>(Cb, As2, n2, 10);
  score_k<<<n2 / 256, 256, 0, stream>>>(xs2, pp + 64, scb, n2);
  topk_k<<<n2 / 256, 256, 0, stream>>>(scb, perm3, valsb, n2, n3);
  pool_h_k<<<n3 * 32 / 256, 256, 0, stream>>>(xs2, perm3, valsb, hA, n3);
  pool_A_k<<<(int)(((size_t)n3 * n3 + 255) / 256), 256, 0, stream>>>(Cb, perm3, A3, nullptr, n2, 9);
  deg_dinv_k<<<n3 / 4, 256, 0, stream>>>(A3, dinv3, n3);
  xw_scale_k<32><<<n3 / 8, dim3(32, 8), 0, stream>>>(hA, dW + 3072, dinv3, Zb, n3, 32, 0);
  gcn_agg_k<32><<<n3 / 32, 256, 0, stream>>>(A3, Zb, dinv3, db + 96, hB, n3, 1);

  // ---- up path ----
  hipMemcpyAsync(hA, xs2, (size_t)n2 * 32 * 4, hipMemcpyDeviceToDevice, stream);
  scatter_add_k<<<n3 * 32 / 256, 256, 0, stream>>>(hA, perm3, hB, n3);
  xw_scale_k<32><<<n2 / 8, dim3(32, 8), 0, stream>>>(hA, uW, dinv2, Zb, n2, 32, 0);
  gcn_agg_k<32><<<n2 / 32, 256, 0, stream>>>(As2, Zb, dinv2, ub, hB, n2, 1);

  hipMemcpyAsync(hA, xs1, (size_t)n1 * 32 * 4, hipMemcpyDeviceToDevice, stream);
  scatter_add_k<<<n2 * 32 / 256, 256, 0, stream>>>(hA, perm2, hB, n2);
  xw_scale_k<32><<<n1 / 8, dim3(32, 8), 0, stream>>>(hA, uW + 1024, dinv1, Zb, n1, 32, 0);
  gcn_agg_k<32><<<n1 / 32, 256, 0, stream>>>(As1, Zb, dinv1, ub + 32, hB, n1, 1);

  hipMemcpyAsync(hA, xs0, (size_t)n0 * 32 * 4, hipMemcpyDeviceToDevice, stream);
  scatter_add_k<<<n1 * 32 / 256, 256, 0, stream>>>(hA, perm1, hB, n1);
  xw_scale_k<32><<<n0 / 8, dim3(32, 8), 0, stream>>>(hA, uW + 2048, dinv0, Zb, n0, 32, 0);
  gcn_agg_k<32><<<n0 / 32, 256, 0, stream>>>(A, Zb, dinv0, ub + 64, hB, n0, 0);

  // final: x = relu(h); out = gcn(x, A, Wf, bf); log_softmax
  xw_scale_k<7><<<n0 / 8, dim3(32, 8), 0, stream>>>(hB, Wf, dinv0, Zb, n0, 32, 1);
  gcn_agg_k<7><<<n0 / 32, 256, 0, stream>>>(A, Zb, dinv0, bf, otmp, n0, 0);
  logsoftmax_k<<<n0 / 256, 256, 0, stream>>>(otmp, outp, n0);
}

// Round 3
// 1041.224 us; speedup vs baseline: 2.6454x; 1.2570x over previous
//
#include <hip/hip_runtime.h>
#include <hip/hip_bf16.h>
#include <cstdint>

#define N_NODES 4096
#define F_IN    1433
#define N_EDGE  131072

typedef short short8v __attribute__((ext_vector_type(8)));
typedef float f32x4 __attribute__((ext_vector_type(4)));

#define GLOBAL_AS __attribute__((address_space(1)))
#define LDS_AS    __attribute__((address_space(3)))

__device__ __forceinline__ void gload_lds16(const void* g, void* l) {
  __builtin_amdgcn_global_load_lds((const GLOBAL_AS void*)g, (LDS_AS void*)l, 16, 0, 0);
}

__device__ __forceinline__ float bf16_to_f32(unsigned short u) {
  union { unsigned u; float f; } c;
  c.u = ((unsigned)u) << 16;
  return c.f;
}

// ---------------- adjacency build ----------------

__global__ void scatter_edges_k(const int* __restrict__ e0, const int* __restrict__ e1,
                                float* __restrict__ A, unsigned short* __restrict__ Ab,
                                int n, int ne) {
  int t = blockIdx.x * 256 + threadIdx.x;
  if (t >= ne) return;
  int u = e0[t], v = e1[t];
  if (u != v) {
    A[(size_t)u * n + v] = 1.0f;
    A[(size_t)v * n + u] = 1.0f;
    Ab[(size_t)u * n + v] = 0x3F80;  // bf16 1.0
    Ab[(size_t)v * n + u] = 0x3F80;
  }
}

// deg = rowsum(A) + 2 (improved GCN), dinv = 1/sqrt(deg)
__global__ void deg_dinv_k(const float* __restrict__ A, float* __restrict__ dinv, int n) {
  int wid  = (blockIdx.x * blockDim.x + threadIdx.x) >> 6;
  int lane = threadIdx.x & 63;
  if (wid >= n) return;
  const float* row = A + (size_t)wid * n;
  float s = 0.f;
  for (int j = lane * 4; j < n; j += 256) {
    float4 v = *(const float4*)(row + j);
    s += (v.x + v.y) + (v.z + v.w);
  }
#pragma unroll
  for (int off = 32; off > 0; off >>= 1) s += __shfl_down(s, off, 64);
  if (lane == 0) {
    float d = s + 2.0f;
    dinv[wid] = d > 0.f ? 1.0f / sqrtf(d) : 0.f;
  }
}

// ---------------- row gathers (Ap = M[perm, :]) ----------------

__global__ void gather_rows_bf16_k(const unsigned short* __restrict__ src,
                                   const int* __restrict__ perm,
                                   unsigned short* __restrict__ dst, int K, int cbits) {
  // cbits = log2(K/8); one uint4 (8 bf16) per thread
  size_t t = (size_t)blockIdx.x * 256 + threadIdx.x;
  int r  = (int)(t >> cbits);
  int c8 = (int)(t & ((1u << cbits) - 1));
  uint4 v = *(const uint4*)(src + (size_t)perm[r] * K + c8 * 8);
  *(uint4*)(dst + t * 8) = v;
}

__global__ void gather_rows_f32_k(const float* __restrict__ src,
                                  const int* __restrict__ perm,
                                  float* __restrict__ dst, int K, int cbits) {
  // cbits = log2(K/4); one float4 per thread
  size_t t = (size_t)blockIdx.x * 256 + threadIdx.x;
  int r  = (int)(t >> cbits);
  int c4 = (int)(t & ((1u << cbits) - 1));
  float4 v = *(const float4*)(src + (size_t)perm[r] * K + c4 * 4);
  *(float4*)(dst + t * 4) = v;
}

// ---------------- pooled augment via bf16 MFMA ----------------
// out[r][s] = dot(Ap[r,:], Ap[s,:]) + 2*Ap[r][perm[s]], diag 0.
// Ap is M x K bf16 row-major (gathered rows of symmetric M-matrix).
// m97 structure: 128x128 tile, BK=32, 4 waves, global_load_lds x16, dbuf LDS.

__global__ __launch_bounds__(256) void gemm_bf16_pool_k(
    const __hip_bfloat16* __restrict__ Ap, const int* __restrict__ perm,
    float* __restrict__ outF, unsigned short* __restrict__ outB, int M, int K) {
  __shared__ short lds[2][2][128 * 32];
  int nb  = M >> 7;
  int bx  = blockIdx.x % nb;
  int by  = blockIdx.x / nb;
  int row0 = by << 7, col0 = bx << 7;
  int tid = threadIdx.x;
  int wv = tid >> 6, ln = tid & 63;
  int lr = ln & 15, kh = ln >> 4;
  int wr = wv >> 1, wc = wv & 1;

  f32x4 acc[4][4] = {};

  auto stage = [&](int buf, int k0) {
#pragma unroll
    for (int t = 0; t < 2; ++t) {
      int rbase = t ? col0 : row0;  // A rows = row0.., B^T rows = col0..
      short* base = &lds[buf][t][0];
#pragma unroll
      for (int l = 0; l < 2; ++l) {
        int uoff = l * 4096 + wv * 1024;
        int poff = uoff + ln * 16;
        int row  = poff >> 6;     // 64B per row (32 bf16)
        int colb = poff & 63;
        const char* g = (const char*)(Ap + (size_t)(rbase + row) * K + k0) + colb;
        gload_lds16(g, (char*)base + uoff);
      }
    }
  };

  int nt = K >> 5;
  stage(0, 0);
  int cur = 0;
  for (int kt = 0; kt < nt; ++kt) {
    __syncthreads();
    if (kt + 1 < nt) stage(cur ^ 1, (kt + 1) << 5);
    const short* Ab = &lds[cur][0][0];
    const short* Bb = &lds[cur][1][0];
    short8v af[4], bfr[4];
#pragma unroll
    for (int m = 0; m < 4; ++m)
      af[m] = *(const short8v*)(Ab + (wr * 64 + m * 16 + lr) * 32 + kh * 8);
#pragma unroll
    for (int q = 0; q < 4; ++q)
      bfr[q] = *(const short8v*)(Bb + (wc * 64 + q * 16 + lr) * 32 + kh * 8);
#pragma unroll
    for (int m = 0; m < 4; ++m)
#pragma unroll
      for (int q = 0; q < 4; ++q)
        acc[m][q] = __builtin_amdgcn_mfma_f32_16x16x32_bf16(af[m], bfr[q], acc[m][q], 0, 0, 0);
    cur ^= 1;
  }

#pragma unroll
  for (int q = 0; q < 4; ++q) {
    int col = col0 + wc * 64 + q * 16 + lr;
    int pc  = perm[col];
#pragma unroll
    for (int m = 0; m < 4; ++m) {
      int rb = row0 + wr * 64 + m * 16 + kh * 4;
#pragma unroll
      for (int r = 0; r < 4; ++r) {
        int row = rb + r;
        float v = acc[m][q][r] +
                  2.0f * bf16_to_f32(((const unsigned short*)Ap)[(size_t)row * K + pc]);
        if (row == col) v = 0.f;
        outF[(size_t)row * M + col] = v;
        if (outB) {
          union { float f; unsigned u; } c; c.f = v;
          outB[(size_t)row * M + col] = (unsigned short)(c.u >> 16);  // exact small int
        }
      }
    }
  }
}

// ---------------- pooled augment f32 (level 3: values not bf16-exact) ----------
// 32x32 tile, 2x2 per thread, K-transposed LDS for float2 reads.

__global__ __launch_bounds__(256) void gemm_f32_pool_k(
    const float* __restrict__ Ap, const int* __restrict__ perm,
    float* __restrict__ outF, int M, int K) {
  __shared__ float As[32][33];
  __shared__ float Bs[32][33];
  int nb = M >> 5;
  int bx = blockIdx.x % nb, by = blockIdx.x / nb;
  int row0 = by << 5, col0 = bx << 5;
  int tid = threadIdx.x;
  int tr = tid >> 4, tc = tid & 15;
  int lr = tid >> 3, lq = (tid & 7) * 4;
  float acc[2][2] = {};
  for (int k0 = 0; k0 < K; k0 += 32) {
    float4 av = *(const float4*)(Ap + (size_t)(row0 + lr) * K + k0 + lq);
    float4 bv = *(const float4*)(Ap + (size_t)(col0 + lr) * K + k0 + lq);
    __syncthreads();
    As[lq + 0][lr] = av.x; As[lq + 1][lr] = av.y;
    As[lq + 2][lr] = av.z; As[lq + 3][lr] = av.w;
    Bs[lq + 0][lr] = bv.x; Bs[lq + 1][lr] = bv.y;
    Bs[lq + 2][lr] = bv.z; Bs[lq + 3][lr] = bv.w;
    __syncthreads();
#pragma unroll
    for (int k = 0; k < 32; ++k) {
      float2 a = *(const float2*)&As[k][tr * 2];
      float2 b = *(const float2*)&Bs[k][tc * 2];
      acc[0][0] += a.x * b.x; acc[0][1] += a.x * b.y;
      acc[1][0] += a.y * b.x; acc[1][1] += a.y * b.y;
    }
  }
#pragma unroll
  for (int j = 0; j < 2; ++j) {
    int col = col0 + tc * 2 + j;
    int pc = perm[col];
#pragma unroll
    for (int i = 0; i < 2; ++i) {
      int row = row0 + tr * 2 + i;
      float v = acc[i][j] + 2.0f * Ap[(size_t)row * K + pc];
      if (row == col) v = 0.f;
      outF[(size_t)row * M + col] = v;
    }
  }
}

// ---------------- Z = dinv_i * (X @ W), optional relu on X ----------------
template <int K2>
__global__ void xw_scale_k(const float* __restrict__ X, const float* __restrict__ W,
                           const float* __restrict__ dinv, float* __restrict__ Z,
                           int n, int K1, int relu_in) {
  __shared__ float Xs[8][128];
  int tx = threadIdx.x, ty = threadIdx.y;
  int i0 = blockIdx.x * 8;
  int tid = ty * 32 + tx;
  float acc = 0.f;
  for (int k0 = 0; k0 < K1; k0 += 128) {
    __syncthreads();
#pragma unroll
    for (int l = 0; l < 4; ++l) {
      int idx = tid + l * 256;
      int r = idx >> 7, kk = idx & 127;
      float xv = (k0 + kk < K1) ? X[(size_t)(i0 + r) * K1 + k0 + kk] : 0.f;
      if (relu_in) xv = fmaxf(xv, 0.f);
      Xs[r][kk] = xv;
    }
    __syncthreads();
    if (tx < K2) {
      int lim = min(128, K1 - k0);
      for (int kk = 0; kk < lim; ++kk)
        acc += Xs[ty][kk] * W[(size_t)(k0 + kk) * K2 + tx];
    }
  }
  if (tx < K2) Z[(size_t)(i0 + ty) * K2 + tx] = dinv[i0 + ty] * acc;
}

// ---------------- out = act(dinv_i*(A@Z + 2*Z_i) + b) ----------------
// 16 rows/block (2x grid vs 32); A read as bf16 where exact (BF16A=1).
template <int HC, int BF16A>
__global__ __launch_bounds__(256) void gcn_agg_k(const void* __restrict__ Av,
                                                 const float* __restrict__ Z,
                                                 const float* __restrict__ dinv,
                                                 const float* __restrict__ bias,
                                                 float* __restrict__ out, int n, int relu) {
  __shared__ float As[16][68];
  __shared__ float Zs[64][32];
  int tid = threadIdx.x;
  int rt = tid >> 4, cg = tid & 15;
  int lr = tid >> 4, lq = (tid & 15) * 4;
  int row0 = blockIdx.x * 16;
  float acc0 = 0.f, acc1 = 0.f;
  for (int j0 = 0; j0 < n; j0 += 64) {
    __syncthreads();
    if (BF16A) {
      const unsigned short* Ab = (const unsigned short*)Av;
      ushort4 a4 = *(const ushort4*)(Ab + (size_t)(row0 + lr) * n + j0 + lq);
      As[lr][lq + 0] = bf16_to_f32(a4.x);
      As[lr][lq + 1] = bf16_to_f32(a4.y);
      As[lr][lq + 2] = bf16_to_f32(a4.z);
      As[lr][lq + 3] = bf16_to_f32(a4.w);
    } else {
      *(float4*)&As[lr][lq] =
          *(const float4*)((const float*)Av + (size_t)(row0 + lr) * n + j0 + lq);
    }
    if (HC == 32) {
#pragma unroll
      for (int l = 0; l < 2; ++l) {
        int f = tid + l * 256;
        int r = f >> 3, q = (f & 7) * 4;
        *(float4*)&Zs[r][q] = *(const float4*)(Z + (size_t)(j0 + r) * 32 + q);
      }
    } else {
      for (int l = tid; l < 64 * HC; l += 256) {
        int r = l / HC, q = l - r * HC;
        Zs[r][q] = Z[(size_t)(j0 + r) * HC + q];
      }
    }
    __syncthreads();
#pragma unroll
    for (int j = 0; j < 64; ++j) {
      float av = As[rt][j];
      float2 zv = *(const float2*)&Zs[j][cg * 2];
      acc0 += av * zv.x;
      acc1 += av * zv.y;
    }
  }
  int row = row0 + rt;
  float di = dinv[row];
  int c0 = cg * 2;
  if (c0 < HC) {
    float zi = Z[(size_t)row * HC + c0];
    float v = di * (acc0 + 2.f * zi) + bias[c0];
    if (relu) v = fmaxf(v, 0.f);
    out[(size_t)row * HC + c0] = v;
  }
  if (c0 + 1 < HC) {
    float zi = Z[(size_t)row * HC + c0 + 1];
    float v = di * (acc1 + 2.f * zi) + bias[c0 + 1];
    if (relu) v = fmaxf(v, 0.f);
    out[(size_t)row * HC + c0 + 1] = v;
  }
}

// ---------------- top-k machinery ----------------

__global__ void score_k(const float* __restrict__ h, const float* __restrict__ p,
                        float* __restrict__ score, int n) {
  int i = blockIdx.x * 256 + threadIdx.x;
  if (i >= n) return;
  float s = 0.f, pn = 0.f;
#pragma unroll
  for (int c = 0; c < 32; ++c) {
    float pc = p[c];
    s += h[(size_t)i * 32 + c] * pc;
    pn += pc * pc;
  }
  score[i] = tanhf(s / sqrtf(pn));
}

__global__ void topk_k(const float* __restrict__ score, int* __restrict__ perm,
                       float* __restrict__ vals, int n, int k) {
  __shared__ float sc[256];
  int i = blockIdx.x * 256 + threadIdx.x;
  float si = score[i];
  int rank = 0;
  for (int j0 = 0; j0 < n; j0 += 256) {
    __syncthreads();
    sc[threadIdx.x] = score[j0 + threadIdx.x];
    __syncthreads();
#pragma unroll 8
    for (int jj = 0; jj < 256; ++jj) {
      float sj = sc[jj];
      rank += (sj > si) || ((sj == si) && ((j0 + jj) < i));
    }
  }
  if (rank < k) { perm[rank] = i; vals[rank] = si; }
}

__global__ void pool_h_k(const float* __restrict__ h, const int* __restrict__ perm,
                         const float* __restrict__ vals, float* __restrict__ out, int k) {
  int idx = blockIdx.x * 256 + threadIdx.x;
  if (idx >= k * 32) return;
  int r = idx >> 5, c = idx & 31;
  out[idx] = h[(size_t)perm[r] * 32 + c] * vals[r];
}

__global__ void scatter_add_k(float* __restrict__ buf, const int* __restrict__ perm,
                              const float* __restrict__ h, int k) {
  int idx = blockIdx.x * 256 + threadIdx.x;
  if (idx >= k * 32) return;
  int r = idx >> 5, c = idx & 31;
  buf[(size_t)perm[r] * 32 + c] += h[idx];
}

__global__ void logsoftmax_k(const float* __restrict__ z, float* __restrict__ out, int n) {
  int i = blockIdx.x * 256 + threadIdx.x;
  if (i >= n) return;
  const float* zp = z + (size_t)i * 7;
  float m = zp[0];
#pragma unroll
  for (int c = 1; c < 7; ++c) m = fmaxf(m, zp[c]);
  float ssum = 0.f;
#pragma unroll
  for (int c = 0; c < 7; ++c) ssum += expf(zp[c] - m);
  float ls = logf(ssum);
  float* op = out + (size_t)i * 7;
#pragma unroll
  for (int c = 0; c < 7; ++c) op[c] = zp[c] - m - ls;
}

// ---------------- host orchestration ----------------

extern "C" void kernel_launch(void* const* d_in, const int* in_sizes, int n_in,
                              void* d_out, int out_size, void* d_ws, size_t ws_size,
                              hipStream_t stream) {
  (void)in_sizes; (void)n_in; (void)out_size; (void)ws_size;
  const float* x   = (const float*)d_in[0];
  const int*  eidx = (const int*)d_in[1];
  const float* Wi  = (const float*)d_in[2];
  const float* bi  = (const float*)d_in[3];
  const float* dW  = (const float*)d_in[4];
  const float* db  = (const float*)d_in[5];
  const float* pp  = (const float*)d_in[6];
  const float* uW  = (const float*)d_in[7];
  const float* ub  = (const float*)d_in[8];
  const float* Wf  = (const float*)d_in[9];
  const float* bf  = (const float*)d_in[10];
  float* outp = (float*)d_out;

  char* ws = (char*)d_ws;
  size_t off = 0;
  auto alloc = [&](size_t bytes) -> char* {
    char* p = ws + off;
    off += (bytes + 255) & ~(size_t)255;
    return p;
  };
  const int n0 = 4096, n1 = 2048, n2 = 1024, n3 = 512;
  float* A     = (float*)alloc((size_t)n0 * n0 * 4);
  unsigned short* Abf   = (unsigned short*)alloc((size_t)n0 * n0 * 2);
  float* As1   = (float*)alloc((size_t)n1 * n1 * 4);
  unsigned short* As1bf = (unsigned short*)alloc((size_t)n1 * n1 * 2);
  float* As2   = (float*)alloc((size_t)n2 * n2 * 4);
  float* A3    = (float*)alloc((size_t)n3 * n3 * 4);
  unsigned short* Ap  = (unsigned short*)alloc((size_t)n1 * n0 * 2);  // 2048x4096 bf16
  unsigned short* Ap2 = (unsigned short*)alloc((size_t)n2 * n1 * 2);  // 1024x2048 bf16
  float* Ap3 = (float*)alloc((size_t)n3 * n2 * 4);                    // 512x1024 f32
  float* dinv0 = (float*)alloc(n0 * 4);
  float* dinv1 = (float*)alloc(n1 * 4);
  float* dinv2 = (float*)alloc(n2 * 4);
  float* dinv3 = (float*)alloc(n3 * 4);
  float* Zb    = (float*)alloc((size_t)n0 * 32 * 4);
  float* x0    = (float*)alloc((size_t)n0 * 32 * 4);
  float* xs0   = (float*)alloc((size_t)n0 * 32 * 4);
  float* xs1   = (float*)alloc((size_t)n1 * 32 * 4);
  float* xs2   = (float*)alloc((size_t)n2 * 32 * 4);
  float* hA    = (float*)alloc((size_t)n0 * 32 * 4);
  float* hB    = (float*)alloc((size_t)n0 * 32 * 4);
  float* scb   = (float*)alloc(n0 * 4);
  float* valsb = (float*)alloc(n0 * 4);
  int* perm1   = (int*)alloc(n1 * 4);
  int* perm2   = (int*)alloc(n2 * 4);
  int* perm3   = (int*)alloc(n3 * 4);
  float* otmp  = (float*)alloc((size_t)n0 * 7 * 4);

  // adjacency (f32 + bf16 copies)
  hipMemsetAsync(A, 0, (size_t)n0 * n0 * 4, stream);
  hipMemsetAsync(Abf, 0, (size_t)n0 * n0 * 2, stream);
  scatter_edges_k<<<N_EDGE / 256, 256, 0, stream>>>(eidx, eidx + N_EDGE, A, Abf, n0, N_EDGE);
  deg_dinv_k<<<n0 / 4, 256, 0, stream>>>(A, dinv0, n0);

  // gcn0 + gcn1 (down_W[0])
  xw_scale_k<32><<<n0 / 8, dim3(32, 8), 0, stream>>>(x, Wi, dinv0, Zb, n0, F_IN, 0);
  gcn_agg_k<32, 1><<<n0 / 16, 256, 0, stream>>>(Abf, Zb, dinv0, bi, x0, n0, 1);
  xw_scale_k<32><<<n0 / 8, dim3(32, 8), 0, stream>>>(x0, dW, dinv0, Zb, n0, 32, 0);
  gcn_agg_k<32, 1><<<n0 / 16, 256, 0, stream>>>(Abf, Zb, dinv0, db, xs0, n0, 1);

  // ---- level 1: As1 = (A@A + 2A)[perm1][perm1] via pooled MFMA ----
  score_k<<<n0 / 256, 256, 0, stream>>>(xs0, pp, scb, n0);
  topk_k<<<n0 / 256, 256, 0, stream>>>(scb, perm1, valsb, n0, n1);
  pool_h_k<<<n1 * 32 / 256, 256, 0, stream>>>(xs0, perm1, valsb, hA, n1);
  gather_rows_bf16_k<<<(int)((size_t)n1 * n0 / 8 / 256), 256, 0, stream>>>(Abf, perm1, Ap, n0, 9);
  gemm_bf16_pool_k<<<(n1 / 128) * (n1 / 128), 256, 0, stream>>>(
      (const __hip_bfloat16*)Ap, perm1, As1, As1bf, n1, n0);
  deg_dinv_k<<<n1 / 4, 256, 0, stream>>>(As1, dinv1, n1);
  xw_scale_k<32><<<n1 / 8, dim3(32, 8), 0, stream>>>(hA, dW + 1024, dinv1, Zb, n1, 32, 0);
  gcn_agg_k<32, 1><<<n1 / 16, 256, 0, stream>>>(As1bf, Zb, dinv1, db + 32, xs1, n1, 1);

  // ---- level 2: As2 = (As1@As1 + 2As1)[perm2][perm2] (values <=~20, bf16 exact in) ----
  score_k<<<n1 / 256, 256, 0, stream>>>(xs1, pp + 32, scb, n1);
  topk_k<<<n1 / 256, 256, 0, stream>>>(scb, perm2, valsb, n1, n2);
  pool_h_k<<<n2 * 32 / 256, 256, 0, stream>>>(xs1, perm2, valsb, hA, n2);
  gather_rows_bf16_k<<<(int)((size_t)n2 * n1 / 8 / 256), 256, 0, stream>>>(As1bf, perm2, Ap2, n1, 8);
  gemm_bf16_pool_k<<<(n2 / 128) * (n2 / 128), 256, 0, stream>>>(
      (const __hip_bfloat16*)Ap2, perm2, As2, nullptr, n2, n1);
  deg_dinv_k<<<n2 / 4, 256, 0, stream>>>(As2, dinv2, n2);
  xw_scale_k<32><<<n2 / 8, dim3(32, 8), 0, stream>>>(hA, dW + 2048, dinv2, Zb, n2, 32, 0);
  gcn_agg_k<32, 0><<<n2 / 16, 256, 0, stream>>>(As2, Zb, dinv2, db + 64, xs2, n2, 1);

  // ---- level 3: A3 = (As2@As2 + 2As2)[perm3][perm3], f32 (values not bf16-exact) ----
  score_k<<<n2 / 256, 256, 0, stream>>>(xs2, pp + 64, scb, n2);
  topk_k<<<n2 / 256, 256, 0, stream>>>(scb, perm3, valsb, n2, n3);
  pool_h_k<<<n3 * 32 / 256, 256, 0, stream>>>(xs2, perm3, valsb, hA, n3);
  gather_rows_f32_k<<<(int)((size_t)n3 * n2 / 4 / 256), 256, 0, stream>>>(As2, perm3, Ap3, n2, 8);
  gemm_f32_pool_k<<<(n3 / 32) * (n3 / 32), 256, 0, stream>>>(Ap3, perm3, A3, n3, n2);
  deg_dinv_k<<<n3 / 4, 256, 0, stream>>>(A3, dinv3, n3);
  xw_scale_k<32><<<n3 / 8, dim3(32, 8), 0, stream>>>(hA, dW + 3072, dinv3, Zb, n3, 32, 0);
  gcn_agg_k<32, 0><<<n3 / 16, 256, 0, stream>>>(A3, Zb, dinv3, db + 96, hB, n3, 1);

  // ---- up path ----
  hipMemcpyAsync(hA, xs2, (size_t)n2 * 32 * 4, hipMemcpyDeviceToDevice, stream);
  scatter_add_k<<<n3 * 32 / 256, 256, 0, stream>>>(hA, perm3, hB, n3);
  xw_scale_k<32><<<n2 / 8, dim3(32, 8), 0, stream>>>(hA, uW, dinv2, Zb, n2, 32, 0);
  gcn_agg_k<32, 0><<<n2 / 16, 256, 0, stream>>>(As2, Zb, dinv2, ub, hB, n2, 1);

  hipMemcpyAsync(hA, xs1, (size_t)n1 * 32 * 4, hipMemcpyDeviceToDevice, stream);
  scatter_add_k<<<n2 * 32 / 256, 256, 0, stream>>>(hA, perm2, hB, n2);
  xw_scale_k<32><<<n1 / 8, dim3(32, 8), 0, stream>>>(hA, uW + 1024, dinv1, Zb, n1, 32, 0);
  gcn_agg_k<32, 1><<<n1 / 16, 256, 0, stream>>>(As1bf, Zb, dinv1, ub + 32, hB, n1, 1);

  hipMemcpyAsync(hA, xs0, (size_t)n0 * 32 * 4, hipMemcpyDeviceToDevice, stream);
  scatter_add_k<<<n1 * 32 / 256, 256, 0, stream>>>(hA, perm1, hB, n1);
  xw_scale_k<32><<<n0 / 8, dim3(32, 8), 0, stream>>>(hA, uW + 2048, dinv0, Zb, n0, 32, 0);
  gcn_agg_k<32, 1><<<n0 / 16, 256, 0, stream>>>(Abf, Zb, dinv0, ub + 64, hB, n0, 0);

  // final: x = relu(h); out = gcn(x, A, Wf, bf); log_softmax
  xw_scale_k<7><<<n0 / 8, dim3(32, 8), 0, stream>>>(hB, Wf, dinv0, Zb, n0, 32, 1);
  gcn_agg_k<7, 1><<<n0 / 16, 256, 0, stream>>>(Abf, Zb, dinv0, bf, otmp, n0, 0);
  logsoftmax_k<<<n0 / 256, 256, 0, stream>>>(otmp, outp, n0);
}